// Round 4
// baseline (2794.938 us; speedup 1.0000x reference)
//
#include <hip/hip_runtime.h>
#include <hip/hip_bf16.h>
#include <math.h>

// Problem constants (from reference)
#define kN  100000   // nodes
#define kE  1000000  // message edges
#define kEP 100000   // pos/neg link-pred edges
// H=64, NF=128, EF=32, L=2

__device__ __forceinline__ int rfl(int v) { return __builtin_amdgcn_readfirstlane(v); }

// ---------------------------------------------------------------------------
// Precompute Wp = edge_w @ mlp1_w[128:192,:] (folds the linear pe operand of
// the head MLP1), bp = edge_b @ mlp1_w[128:192,:].
// ---------------------------------------------------------------------------
__global__ void k_head_pre(const float* __restrict__ edge_w,
                           const float* __restrict__ edge_b,
                           const float* __restrict__ m1w,
                           float* __restrict__ Wp, float* __restrict__ bp) {
  const int c = threadIdx.x;          // 0..63 output channel
  const int j = blockIdx.x;           // 0..32
  const float* __restrict__ src = (j < 32) ? (edge_w + j * 64) : edge_b;
  float s = 0.f;
#pragma unroll 8
  for (int m = 0; m < 64; ++m) s = fmaf(src[m], m1w[(128 + m) * 64 + c], s);
  if (j < 32) Wp[j * 64 + c] = s; else bp[c] = s;
}

// ---------------------------------------------------------------------------
// h = x @ node_w + node_b   [1e5,128]@[128,64]; blocked node ownership so each
// wave streams x sequentially.
// ---------------------------------------------------------------------------
__global__ __launch_bounds__(256) void k_node_enc(const float* __restrict__ x,
                                                  const float* __restrict__ w,
                                                  const float* __restrict__ b,
                                                  float* __restrict__ h) {
  const int lane = threadIdx.x & 63;
  const int wid  = blockIdx.x * (blockDim.x >> 6) + (threadIdx.x >> 6);
  const int nw   = gridDim.x * (blockDim.x >> 6);
  float wreg[128];
#pragma unroll
  for (int k = 0; k < 128; ++k) wreg[k] = w[k * 64 + lane];
  const float bias = b[lane];
  const int npw  = (kN + nw - 1) / nw;
  const int nbeg = wid * npw;
  const int nend = (nbeg + npw < kN) ? nbeg + npw : kN;
  for (int n = nbeg; n < nend; ++n) {
    const float* __restrict__ row = x + (size_t)n * 128;
    float a0 = bias, a1 = 0.f;
#pragma unroll
    for (int k = 0; k < 128; k += 2) {
      a0 = fmaf(row[k],     wreg[k],     a0);
      a1 = fmaf(row[k + 1], wreg[k + 1], a1);
    }
    h[(size_t)n * 64 + lane] = a0 + a1;
  }
}

// ---------------------------------------------------------------------------
// CSR build step 1: histogram of dst degrees.
// ---------------------------------------------------------------------------
__global__ __launch_bounds__(256) void k_hist(const int* __restrict__ ei,
                                              int* __restrict__ deg) {
  const int tid    = blockIdx.x * blockDim.x + threadIdx.x;
  const int stride = gridDim.x * blockDim.x;
  for (int e = tid; e < kE; e += stride) atomicAdd(&deg[ei[kE + e]], 1);
}

// ---------------------------------------------------------------------------
// Hierarchical exclusive scan of deg[kN] -> rowstart (3 small kernels).
// ---------------------------------------------------------------------------
#define SCAN_NB 98    // ceil(kN / 1024)
__global__ __launch_bounds__(1024) void k_scanA(const int* __restrict__ deg,
                                                int* __restrict__ rowstart,
                                                int* __restrict__ btot) {
  __shared__ int part[1024];
  const int t = threadIdx.x;
  const int i = blockIdx.x * 1024 + t;
  const int s = (i < kN) ? deg[i] : 0;
  part[t] = s;
  __syncthreads();
  for (int off = 1; off < 1024; off <<= 1) {
    const int v = (t >= off) ? part[t - off] : 0;
    __syncthreads();
    part[t] += v;
    __syncthreads();
  }
  if (i < kN) rowstart[i] = part[t] - s;            // block-local exclusive
  if (t == 1023) btot[blockIdx.x] = part[1023];
}

__global__ __launch_bounds__(128) void k_scanB(int* __restrict__ btot,
                                               int* __restrict__ boff) {
  __shared__ int part[128];
  const int t = threadIdx.x;
  const int s = (t < SCAN_NB) ? btot[t] : 0;
  part[t] = s;
  __syncthreads();
  for (int off = 1; off < 128; off <<= 1) {
    const int v = (t >= off) ? part[t - off] : 0;
    __syncthreads();
    part[t] += v;
    __syncthreads();
  }
  if (t < SCAN_NB) boff[t] = part[t] - s;           // exclusive block offsets
}

__global__ __launch_bounds__(1024) void k_scanC(int* __restrict__ rowstart,
                                                const int* __restrict__ boff) {
  const int i = blockIdx.x * 1024 + threadIdx.x;
  if (i < kN) rowstart[i] += boff[blockIdx.x];
  if (i == 0) rowstart[kN] = kE;                    // total is always kE
}

// ---------------------------------------------------------------------------
// CSR build step 3: assign each edge its bucket slot; emit the permutation
// (eperm[e] = pos) and the src array in CSR order. cursor[] must be zeroed.
// ---------------------------------------------------------------------------
__global__ __launch_bounds__(256) void k_fill(const int* __restrict__ ei,
                                              const int* __restrict__ rowstart,
                                              int* __restrict__ cursor,
                                              int* __restrict__ eperm,
                                              int* __restrict__ srcs) {
  const int tid    = blockIdx.x * blockDim.x + threadIdx.x;
  const int stride = gridDim.x * blockDim.x;
  for (int e = tid; e < kE; e += stride) {
    const int dst = ei[kE + e];
    const int pos = rowstart[dst] + atomicAdd(&cursor[dst], 1);
    eperm[e] = pos;
    srcs[pos] = ei[e];
  }
}

// ---------------------------------------------------------------------------
// Edge embedding (layer-invariant, computed ONCE):
//   ea[eperm[e]] = bf16( edge_attr[e]@edge_w + edge_b )
// Sequential coalesced eattr reads; random (non-blocking) row writes.
// ---------------------------------------------------------------------------
__global__ __launch_bounds__(256) void k_edge_emb(const int* __restrict__ eperm,
                                                  const float* __restrict__ eattr,
                                                  const float* __restrict__ ew,
                                                  const float* __restrict__ eb,
                                                  __hip_bfloat16* __restrict__ ea) {
  const int lane = threadIdx.x & 63;
  const int wid  = blockIdx.x * (blockDim.x >> 6) + (threadIdx.x >> 6);
  const int nw   = gridDim.x * (blockDim.x >> 6);
  float wreg[32];
#pragma unroll
  for (int k = 0; k < 32; ++k) wreg[k] = ew[k * 64 + lane];
  const float bias = eb[lane];
  const int epw  = (kE + nw - 1) / nw;
  const int ebeg = wid * epw;
  const int eend = (ebeg + epw < kE) ? ebeg + epw : kE;
  for (int e = ebeg; e < eend; ++e) {
    const float* __restrict__ row = eattr + (size_t)e * 32;   // sequential
    float a0 = bias, a1 = 0.f;
#pragma unroll
    for (int k = 0; k < 32; k += 2) {
      a0 = fmaf(row[k],     wreg[k],     a0);
      a1 = fmaf(row[k + 1], wreg[k + 1], a1);
    }
    const int pos = eperm[e];                                 // sequential
    ea[(size_t)pos * 64 + lane] = __float2bfloat16(a0 + a1);  // random write
  }
}

// ---------------------------------------------------------------------------
// Streaming pull aggregation (blocked node ownership + unroll-4):
//   agg[n] = sum_p relu( ea[p] + h[srcs[p]] ),  p in [rowstart[n],rowstart[n+1])
// Each wave owns ~13 consecutive nodes -> its CSR slice is contiguous.
// ---------------------------------------------------------------------------
__global__ __launch_bounds__(256) void k_aggr_s(const float* __restrict__ h,
                                                const __hip_bfloat16* __restrict__ ea,
                                                const int* __restrict__ srcs,
                                                const int* __restrict__ rowstart,
                                                float* __restrict__ agg) {
  const int lane = threadIdx.x & 63;
  const int wid  = blockIdx.x * (blockDim.x >> 6) + (threadIdx.x >> 6);
  const int nw   = gridDim.x * (blockDim.x >> 6);
  const int npw  = (kN + nw - 1) / nw;
  const int nbeg = wid * npw;
  const int nend = (nbeg + npw < kN) ? nbeg + npw : kN;
  if (nbeg >= kN) return;
  int pnext = rowstart[nbeg];
  for (int n = nbeg; n < nend; ++n) {
    const int p0 = pnext;
    const int p1 = rowstart[n + 1];
    pnext = p1;
    float acc = 0.f;
    int p = p0;
    for (; p + 3 < p1; p += 4) {
      const int s0 = srcs[p], s1 = srcs[p + 1], s2 = srcs[p + 2], s3 = srcs[p + 3];
      const float e0 = __bfloat162float(ea[(size_t)p * 64 + lane]);
      const float e1 = __bfloat162float(ea[(size_t)(p + 1) * 64 + lane]);
      const float e2 = __bfloat162float(ea[(size_t)(p + 2) * 64 + lane]);
      const float e3 = __bfloat162float(ea[(size_t)(p + 3) * 64 + lane]);
      const float h0 = h[(size_t)s0 * 64 + lane];
      const float h1 = h[(size_t)s1 * 64 + lane];
      const float h2 = h[(size_t)s2 * 64 + lane];
      const float h3 = h[(size_t)s3 * 64 + lane];
      acc += fmaxf(e0 + h0, 0.f) + fmaxf(e1 + h1, 0.f)
           + fmaxf(e2 + h2, 0.f) + fmaxf(e3 + h3, 0.f);
    }
    for (; p < p1; ++p) {
      const int s = srcs[p];
      acc += fmaxf(__bfloat162float(ea[(size_t)p * 64 + lane])
                   + h[(size_t)s * 64 + lane], 0.f);
    }
    agg[(size_t)n * 64 + lane] = acc;
  }
}

// ---------------------------------------------------------------------------
// z1 = relu((h+agg) @ w1 + b1)       [1e5,64]@[64,64]
// ---------------------------------------------------------------------------
__global__ __launch_bounds__(256) void k_gemm1(const float* __restrict__ h,
                                               const float* __restrict__ agg,
                                               const float* __restrict__ w,
                                               const float* __restrict__ b,
                                               float* __restrict__ z1) {
  const int lane = threadIdx.x & 63;
  const int wid  = blockIdx.x * (blockDim.x >> 6) + (threadIdx.x >> 6);
  const int nw   = gridDim.x * (blockDim.x >> 6);
  float wreg[64];
#pragma unroll
  for (int k = 0; k < 64; ++k) wreg[k] = w[k * 64 + lane];
  const float bias = b[lane];
  const int npw  = (kN + nw - 1) / nw;
  const int nbeg = wid * npw;
  const int nend = (nbeg + npw < kN) ? nbeg + npw : kN;
  for (int n = nbeg; n < nend; ++n) {
    const float* __restrict__ hr = h   + (size_t)n * 64;
    const float* __restrict__ ar = agg + (size_t)n * 64;
    float a0 = bias, a1 = 0.f;
#pragma unroll
    for (int k = 0; k < 64; k += 2) {
      a0 = fmaf(hr[k]     + ar[k],     wreg[k],     a0);
      a1 = fmaf(hr[k + 1] + ar[k + 1], wreg[k + 1], a1);
    }
    z1[(size_t)n * 64 + lane] = fmaxf(a0 + a1, 0.f);
  }
}

// ---------------------------------------------------------------------------
// z = z1 @ w2 + b2, plus per-channel sum / sumsq partials for BatchNorm.
// ---------------------------------------------------------------------------
__global__ __launch_bounds__(256) void k_gemm2(const float* __restrict__ z1,
                                               const float* __restrict__ w,
                                               const float* __restrict__ b,
                                               float* __restrict__ z,
                                               float* __restrict__ bnsum,
                                               float* __restrict__ bnsq) {
  __shared__ float redS[4][64];
  __shared__ float redQ[4][64];
  const int lane = threadIdx.x & 63;
  const int wv   = threadIdx.x >> 6;
  const int wid  = blockIdx.x * (blockDim.x >> 6) + wv;
  const int nw   = gridDim.x * (blockDim.x >> 6);
  float wreg[64];
#pragma unroll
  for (int k = 0; k < 64; ++k) wreg[k] = w[k * 64 + lane];
  const float bias = b[lane];
  float lsum = 0.f, lsq = 0.f;
  const int npw  = (kN + nw - 1) / nw;
  const int nbeg = wid * npw;
  const int nend = (nbeg + npw < kN) ? nbeg + npw : kN;
  for (int n = nbeg; n < nend; ++n) {
    const float* __restrict__ r = z1 + (size_t)n * 64;
    float a0 = bias, a1 = 0.f;
#pragma unroll
    for (int k = 0; k < 64; k += 2) {
      a0 = fmaf(r[k],     wreg[k],     a0);
      a1 = fmaf(r[k + 1], wreg[k + 1], a1);
    }
    const float zv = a0 + a1;
    z[(size_t)n * 64 + lane] = zv;
    lsum += zv;
    lsq = fmaf(zv, zv, lsq);
  }
  redS[wv][lane] = lsum;
  redQ[wv][lane] = lsq;
  __syncthreads();
  if (threadIdx.x < 64) {
    float s = redS[0][lane] + redS[1][lane] + redS[2][lane] + redS[3][lane];
    float q = redQ[0][lane] + redQ[1][lane] + redQ[2][lane] + redQ[3][lane];
    atomicAdd(&bnsum[lane], s);
    atomicAdd(&bnsq[lane], q);
  }
}

// ---------------------------------------------------------------------------
// BN finalize: per-channel scale/shift from global sums.
// ---------------------------------------------------------------------------
__global__ void k_bnfin(const float* __restrict__ s, const float* __restrict__ q,
                        const float* __restrict__ gm, const float* __restrict__ bt,
                        float* __restrict__ scale, float* __restrict__ shift) {
  const int c = threadIdx.x;
  const float inv = 1.0f / (float)kN;
  const float mean = s[c] * inv;
  float var = q[c] * inv - mean * mean;
  var = fmaxf(var, 0.f);
  const float sc = gm[c] * rsqrtf(var + 1e-5f);
  scale[c] = sc;
  shift[c] = bt[c] - mean * sc;
}

// ---------------------------------------------------------------------------
// h = (h + relu(z*scale + shift)) * 0.5   (elementwise, float4)
// ---------------------------------------------------------------------------
__global__ __launch_bounds__(256) void k_bnapply(const float* __restrict__ z,
                                                 float* __restrict__ h,
                                                 const float* __restrict__ scale,
                                                 const float* __restrict__ shift) {
  __shared__ float sc[64], sh[64];
  if (threadIdx.x < 64) { sc[threadIdx.x] = scale[threadIdx.x]; sh[threadIdx.x] = shift[threadIdx.x]; }
  __syncthreads();
  const size_t tid    = (size_t)blockIdx.x * blockDim.x + threadIdx.x;
  const size_t stride = (size_t)gridDim.x * blockDim.x;
  const size_t total  = (size_t)kN * 16;  // float4 groups
  for (size_t i = tid; i < total; i += stride) {
    const int c0 = (int)((i * 4) & 63);
    const float4 zv = ((const float4*)z)[i];
    float4 hv = ((float4*)h)[i];
    hv.x = (hv.x + fmaxf(fmaf(zv.x, sc[c0 + 0], sh[c0 + 0]), 0.f)) * 0.5f;
    hv.y = (hv.y + fmaxf(fmaf(zv.y, sc[c0 + 1], sh[c0 + 1]), 0.f)) * 0.5f;
    hv.z = (hv.z + fmaxf(fmaf(zv.z, sc[c0 + 2], sh[c0 + 2]), 0.f)) * 0.5f;
    hv.w = (hv.w + fmaxf(fmaf(zv.w, sc[c0 + 3], sh[c0 + 3]), 0.f)) * 0.5f;
    ((float4*)h)[i] = hv;
  }
}

// ---------------------------------------------------------------------------
// Head stage A:
// f1 = relu( relu(h[a])@W1[0:64] + relu(h[b])@W1[64:128] + eattr@Wp + b1 + bp )
// ---------------------------------------------------------------------------
__global__ __launch_bounds__(256) void k_headA(const float* __restrict__ h,
                                               const int* __restrict__ ei,
                                               const float* __restrict__ eattr,
                                               const float* __restrict__ W1,
                                               const float* __restrict__ b1,
                                               const float* __restrict__ Wp,
                                               const float* __restrict__ bp,
                                               float* __restrict__ f1out) {
  const int lane = threadIdx.x & 63;
  const int wid  = blockIdx.x * (blockDim.x >> 6) + (threadIdx.x >> 6);
  const int nw   = gridDim.x * (blockDim.x >> 6);
  float wa[64], wb[64], wp[32];
#pragma unroll
  for (int k = 0; k < 64; ++k) wa[k] = W1[k * 64 + lane];
#pragma unroll
  for (int k = 0; k < 64; ++k) wb[k] = W1[(64 + k) * 64 + lane];
#pragma unroll
  for (int k = 0; k < 32; ++k) wp[k] = Wp[k * 64 + lane];
  const float bias = b1[lane] + bp[lane];
  const int epw  = (kEP + nw - 1) / nw;
  const int ebeg = wid * epw;
  const int eend = (ebeg + epw < kEP) ? ebeg + epw : kEP;
  for (int e = ebeg; e < eend; ++e) {
    const int a = ei[e];
    const int bnode = ei[kEP + e];
    const float* __restrict__ ha = h + (size_t)a * 64;
    const float* __restrict__ hb = h + (size_t)bnode * 64;
    const float* __restrict__ row = eattr + (size_t)e * 32;
    float a0 = bias, a1 = 0.f, a2 = 0.f;
#pragma unroll
    for (int k = 0; k < 64; ++k) a0 = fmaf(fmaxf(ha[k], 0.f), wa[k], a0);
#pragma unroll
    for (int k = 0; k < 64; ++k) a1 = fmaf(fmaxf(hb[k], 0.f), wb[k], a1);
#pragma unroll
    for (int k = 0; k < 32; ++k) a2 = fmaf(row[k], wp[k], a2);
    f1out[(size_t)e * 64 + lane] = fmaxf(a0 + a1 + a2, 0.f);
  }
}

// ---------------------------------------------------------------------------
// Head stage B: f2 = relu(f1@mlp2+b2) [25]; out = sigmoid(f2@mlp3+b3)
// ---------------------------------------------------------------------------
__global__ __launch_bounds__(256) void k_headB(const float* __restrict__ f1,
                                               const float* __restrict__ W2,
                                               const float* __restrict__ b2,
                                               const float* __restrict__ W3,
                                               const float* __restrict__ b3,
                                               float* __restrict__ out) {
  const int lane = threadIdx.x & 63;
  const int wid  = blockIdx.x * (blockDim.x >> 6) + (threadIdx.x >> 6);
  const int nw   = gridDim.x * (blockDim.x >> 6);
  const int c = (lane < 25) ? lane : 0;
  float w2r[64];
#pragma unroll
  for (int k = 0; k < 64; ++k) w2r[k] = W2[k * 25 + c];
  const float bias2 = b2[c];
  const float w3v = (lane < 25) ? W3[lane] : 0.0f;
  const float b3v = b3[0];
  const int epw  = (kEP + nw - 1) / nw;
  const int ebeg = wid * epw;
  const int eend = (ebeg + epw < kEP) ? ebeg + epw : kEP;
  for (int e = ebeg; e < eend; ++e) {
    const float* __restrict__ r = f1 + (size_t)e * 64;
    float a0 = bias2, a1 = 0.f;
#pragma unroll
    for (int k = 0; k < 64; k += 2) {
      a0 = fmaf(r[k],     w2r[k],     a0);
      a1 = fmaf(r[k + 1], w2r[k + 1], a1);
    }
    float p = fmaxf(a0 + a1, 0.f) * w3v;   // lanes >=25 contribute 0
#pragma unroll
    for (int off = 32; off; off >>= 1) p += __shfl_xor(p, off, 64);
    if (lane == 0) out[e] = 1.0f / (1.0f + expf(-(p + b3v)));
  }
}

// ---------------------------------------------------------------------------
extern "C" void kernel_launch(void* const* d_in, const int* in_sizes, int n_in,
                              void* d_out, int out_size, void* d_ws, size_t ws_size,
                              hipStream_t stream) {
  const float* x      = (const float*)d_in[0];
  const int*   ei     = (const int*)  d_in[1];
  const float* eattr  = (const float*)d_in[2];
  const int*   pei    = (const int*)  d_in[3];
  const float* peat   = (const float*)d_in[4];
  const int*   nei    = (const int*)  d_in[5];
  const float* neat   = (const float*)d_in[6];
  const float* node_w = (const float*)d_in[7];
  const float* node_b = (const float*)d_in[8];
  const float* edge_w = (const float*)d_in[9];
  const float* edge_b = (const float*)d_in[10];
  const float* conv_w1= (const float*)d_in[11];
  const float* conv_b1= (const float*)d_in[12];
  const float* conv_w2= (const float*)d_in[13];
  const float* conv_b2= (const float*)d_in[14];
  const float* gamma  = (const float*)d_in[15];
  const float* beta   = (const float*)d_in[16];
  const float* m1w    = (const float*)d_in[17];
  const float* m1b    = (const float*)d_in[18];
  const float* m2w    = (const float*)d_in[19];
  const float* m2b    = (const float*)d_in[20];
  const float* m3w    = (const float*)d_in[21];
  const float* m3b    = (const float*)d_in[22];

  float* out_pos = (float*)d_out;
  float* out_neg = out_pos + kEP;
  float* h       = out_neg + kEP;          // [N,64] lives in d_out

  // ---- workspace carve-out (alignment-aware; ~214 MB total) ----
  size_t off = 0;
  auto alloc = [&](size_t bytes, size_t align) -> void* {
    off = (off + align - 1) / align * align;
    void* p = (char*)d_ws + off;
    off += bytes;
    return p;
  };
  float* agg      = (float*)alloc((size_t)kN * 64 * 4, 16);
  float* z1       = (float*)alloc((size_t)kN * 64 * 4, 16);   // reused as f1_pos
  float* zz       = (float*)alloc((size_t)kN * 64 * 4, 16);   // reused as f1_neg
  float* bnsum    = (float*)alloc(64 * 4, 16);
  float* bnsq     = (float*)alloc(64 * 4, 16);
  float* scale    = (float*)alloc(64 * 4, 16);
  float* shift    = (float*)alloc(64 * 4, 16);
  float* Wp       = (float*)alloc(32 * 64 * 4, 16);
  float* bp       = (float*)alloc(64 * 4, 16);
  int*   deg      = (int*)  alloc((size_t)kN * 4, 16);        // reused as cursor
  int*   rowstart = (int*)  alloc((size_t)(kN + 1) * 4, 16);
  int*   btot     = (int*)  alloc(128 * 4, 16);
  int*   boff     = (int*)  alloc(128 * 4, 16);
  int*   eperm    = (int*)  alloc((size_t)kE * 4, 16);
  int*   srcs     = (int*)  alloc((size_t)kE * 4, 16);
  __hip_bfloat16* ea = (__hip_bfloat16*)alloc((size_t)kE * 64 * 2, 16);
  (void)ws_size;  // R3 verified ws_size >= 217 MB; this layout needs ~214 MB

  k_head_pre<<<dim3(33), dim3(64), 0, stream>>>(edge_w, edge_b, m1w, Wp, bp);
  k_node_enc<<<dim3(1024), dim3(256), 0, stream>>>(x, node_w, node_b, h);

  // ---- CSR build (layer-invariant) ----
  hipMemsetAsync(deg, 0, kN * sizeof(int), stream);
  k_hist<<<dim3(2048), dim3(256), 0, stream>>>(ei, deg);
  k_scanA<<<dim3(SCAN_NB), dim3(1024), 0, stream>>>(deg, rowstart, btot);
  k_scanB<<<dim3(1), dim3(128), 0, stream>>>(btot, boff);
  k_scanC<<<dim3(SCAN_NB), dim3(1024), 0, stream>>>(rowstart, boff);
  hipMemsetAsync(deg, 0, kN * sizeof(int), stream);   // reuse as cursor
  k_fill<<<dim3(2048), dim3(256), 0, stream>>>(ei, rowstart, deg, eperm, srcs);
  k_edge_emb<<<dim3(2048), dim3(256), 0, stream>>>(eperm, eattr, edge_w, edge_b, ea);

  for (int l = 0; l < 2; ++l) {
    hipMemsetAsync(bnsum, 0, 128 * sizeof(float), stream);
    k_aggr_s<<<dim3(2048), dim3(256), 0, stream>>>(h, ea, srcs, rowstart, agg);
    k_gemm1<<<dim3(1024), dim3(256), 0, stream>>>(h, agg, conv_w1 + l * 4096,
                                                  conv_b1 + l * 64, z1);
    k_gemm2<<<dim3(1024), dim3(256), 0, stream>>>(z1, conv_w2 + l * 4096,
                                                  conv_b2 + l * 64, zz, bnsum, bnsq);
    k_bnfin<<<dim3(1), dim3(64), 0, stream>>>(bnsum, bnsq, gamma + l * 64,
                                              beta + l * 64, scale, shift);
    k_bnapply<<<dim3(2048), dim3(256), 0, stream>>>(zz, h, scale, shift);
  }

  // heads: f1 into z1 (pos) / zz (neg), then MLP2/3 + sigmoid
  k_headA<<<dim3(1024), dim3(256), 0, stream>>>(h, pei, peat, m1w, m1b, Wp, bp, z1);
  k_headA<<<dim3(1024), dim3(256), 0, stream>>>(h, nei, neat, m1w, m1b, Wp, bp, zz);
  k_headB<<<dim3(1024), dim3(256), 0, stream>>>(z1, m2w, m2b, m3w, m3b, out_pos);
  k_headB<<<dim3(1024), dim3(256), 0, stream>>>(zz, m2w, m2b, m3w, m3b, out_neg);
}

// Round 5
// 1283.568 us; speedup vs baseline: 2.1775x; 2.1775x over previous
//
#include <hip/hip_runtime.h>
#include <hip/hip_bf16.h>
#include <math.h>

// Problem constants (from reference)
#define kN  100000   // nodes
#define kE  1000000  // message edges
#define kEP 100000   // pos/neg link-pred edges
// H=64, NF=128, EF=32, L=2

// readfirstlane: forces a wave-uniform value into an SGPR so dependent row
// loads take the scalar (s_load) path. Removing this in R4 caused VGPR=256 +
// scratch spills (WRITE_SIZE 115MB vs 26MB) — keep it on EVERY per-row index.
__device__ __forceinline__ int rfl(int v) { return __builtin_amdgcn_readfirstlane(v); }

// ---------------------------------------------------------------------------
// Precompute Wp = edge_w @ mlp1_w[128:192,:] (folds the linear pe operand of
// the head MLP1), bp = edge_b @ mlp1_w[128:192,:].
// ---------------------------------------------------------------------------
__global__ void k_head_pre(const float* __restrict__ edge_w,
                           const float* __restrict__ edge_b,
                           const float* __restrict__ m1w,
                           float* __restrict__ Wp, float* __restrict__ bp) {
  const int c = threadIdx.x;          // 0..63 output channel
  const int j = blockIdx.x;           // 0..32
  const float* __restrict__ src = (j < 32) ? (edge_w + j * 64) : edge_b;
  float s = 0.f;
#pragma unroll 8
  for (int m = 0; m < 64; ++m) s = fmaf(src[m], m1w[(128 + m) * 64 + c], s);
  if (j < 32) Wp[j * 64 + c] = s; else bp[c] = s;
}

// ---------------------------------------------------------------------------
// h = x @ node_w + node_b   [1e5,128]@[128,64]; blocked node ownership so each
// wave streams x sequentially; rfl keeps the row loads scalar.
// ---------------------------------------------------------------------------
__global__ __launch_bounds__(256) void k_node_enc(const float* __restrict__ x,
                                                  const float* __restrict__ w,
                                                  const float* __restrict__ b,
                                                  float* __restrict__ h) {
  const int lane = threadIdx.x & 63;
  const int wid  = blockIdx.x * (blockDim.x >> 6) + (threadIdx.x >> 6);
  const int nw   = gridDim.x * (blockDim.x >> 6);
  float wreg[128];
#pragma unroll
  for (int k = 0; k < 128; ++k) wreg[k] = w[k * 64 + lane];
  const float bias = b[lane];
  const int npw  = (kN + nw - 1) / nw;
  const int nbeg = wid * npw;
  const int nend = (nbeg + npw < kN) ? nbeg + npw : kN;
  for (int n0 = nbeg; n0 < nend; ++n0) {
    const int n = rfl(n0);
    const float* __restrict__ row = x + (size_t)n * 128;
    float a0 = bias, a1 = 0.f;
#pragma unroll
    for (int k = 0; k < 128; k += 2) {
      a0 = fmaf(row[k],     wreg[k],     a0);
      a1 = fmaf(row[k + 1], wreg[k + 1], a1);
    }
    h[(size_t)n * 64 + lane] = a0 + a1;
  }
}

// ---------------------------------------------------------------------------
// CSR build step 1: histogram of dst degrees.
// ---------------------------------------------------------------------------
__global__ __launch_bounds__(256) void k_hist(const int* __restrict__ ei,
                                              int* __restrict__ deg) {
  const int tid    = blockIdx.x * blockDim.x + threadIdx.x;
  const int stride = gridDim.x * blockDim.x;
  for (int e = tid; e < kE; e += stride) atomicAdd(&deg[ei[kE + e]], 1);
}

// ---------------------------------------------------------------------------
// Hierarchical exclusive scan of deg[kN] -> rowstart (3 small kernels).
// ---------------------------------------------------------------------------
#define SCAN_NB 98    // ceil(kN / 1024)
__global__ __launch_bounds__(1024) void k_scanA(const int* __restrict__ deg,
                                                int* __restrict__ rowstart,
                                                int* __restrict__ btot) {
  __shared__ int part[1024];
  const int t = threadIdx.x;
  const int i = blockIdx.x * 1024 + t;
  const int s = (i < kN) ? deg[i] : 0;
  part[t] = s;
  __syncthreads();
  for (int off = 1; off < 1024; off <<= 1) {
    const int v = (t >= off) ? part[t - off] : 0;
    __syncthreads();
    part[t] += v;
    __syncthreads();
  }
  if (i < kN) rowstart[i] = part[t] - s;            // block-local exclusive
  if (t == 1023) btot[blockIdx.x] = part[1023];
}

__global__ __launch_bounds__(128) void k_scanB(int* __restrict__ btot,
                                               int* __restrict__ boff) {
  __shared__ int part[128];
  const int t = threadIdx.x;
  const int s = (t < SCAN_NB) ? btot[t] : 0;
  part[t] = s;
  __syncthreads();
  for (int off = 1; off < 128; off <<= 1) {
    const int v = (t >= off) ? part[t - off] : 0;
    __syncthreads();
    part[t] += v;
    __syncthreads();
  }
  if (t < SCAN_NB) boff[t] = part[t] - s;           // exclusive block offsets
}

__global__ __launch_bounds__(1024) void k_scanC(int* __restrict__ rowstart,
                                                const int* __restrict__ boff) {
  const int i = blockIdx.x * 1024 + threadIdx.x;
  if (i < kN) rowstart[i] += boff[blockIdx.x];
  if (i == 0) rowstart[kN] = kE;                    // total is always kE
}

// ---------------------------------------------------------------------------
// CSR build step 3: assign each edge its bucket slot; emit the permutation
// (eperm[e] = pos) and the src array in CSR order. cursor[] must be zeroed.
// ---------------------------------------------------------------------------
__global__ __launch_bounds__(256) void k_fill(const int* __restrict__ ei,
                                              const int* __restrict__ rowstart,
                                              int* __restrict__ cursor,
                                              int* __restrict__ eperm,
                                              int* __restrict__ srcs) {
  const int tid    = blockIdx.x * blockDim.x + threadIdx.x;
  const int stride = gridDim.x * blockDim.x;
  for (int e = tid; e < kE; e += stride) {
    const int dst = ei[kE + e];
    const int pos = rowstart[dst] + atomicAdd(&cursor[dst], 1);
    eperm[e] = pos;
    srcs[pos] = ei[e];
  }
}

// ---------------------------------------------------------------------------
// Edge embedding (layer-invariant, computed ONCE):
//   ea[eperm[e]] = bf16( edge_attr[e]@edge_w + edge_b )
// Sequential scalar eattr reads per wave; random (non-blocking) row writes.
// ---------------------------------------------------------------------------
__global__ __launch_bounds__(256) void k_edge_emb(const int* __restrict__ eperm,
                                                  const float* __restrict__ eattr,
                                                  const float* __restrict__ ew,
                                                  const float* __restrict__ eb,
                                                  __hip_bfloat16* __restrict__ ea) {
  const int lane = threadIdx.x & 63;
  const int wid  = blockIdx.x * (blockDim.x >> 6) + (threadIdx.x >> 6);
  const int nw   = gridDim.x * (blockDim.x >> 6);
  float wreg[32];
#pragma unroll
  for (int k = 0; k < 32; ++k) wreg[k] = ew[k * 64 + lane];
  const float bias = eb[lane];
  const int epw  = (kE + nw - 1) / nw;
  const int ebeg = wid * epw;
  const int eend = (ebeg + epw < kE) ? ebeg + epw : kE;
  for (int e0 = ebeg; e0 < eend; ++e0) {
    const int e = rfl(e0);
    const float* __restrict__ row = eattr + (size_t)e * 32;   // sequential scalar
    float a0 = bias, a1 = 0.f;
#pragma unroll
    for (int k = 0; k < 32; k += 2) {
      a0 = fmaf(row[k],     wreg[k],     a0);
      a1 = fmaf(row[k + 1], wreg[k + 1], a1);
    }
    const int pos = rfl(eperm[e]);                            // sequential scalar
    ea[(size_t)pos * 64 + lane] = __float2bfloat16(a0 + a1);  // random write
  }
}

// ---------------------------------------------------------------------------
// Streaming pull aggregation (blocked node ownership + unroll-4):
//   agg[n] = sum_p relu( ea[p] + h[srcs[p]] ),  p in [rowstart[n],rowstart[n+1])
// Each wave owns ~13 consecutive nodes -> its CSR slice is contiguous.
// ---------------------------------------------------------------------------
__global__ __launch_bounds__(256) void k_aggr_s(const float* __restrict__ h,
                                                const __hip_bfloat16* __restrict__ ea,
                                                const int* __restrict__ srcs,
                                                const int* __restrict__ rowstart,
                                                float* __restrict__ agg) {
  const int lane = threadIdx.x & 63;
  const int wid  = blockIdx.x * (blockDim.x >> 6) + (threadIdx.x >> 6);
  const int nw   = gridDim.x * (blockDim.x >> 6);
  const int npw  = (kN + nw - 1) / nw;
  const int nbeg = wid * npw;
  const int nend = (nbeg + npw < kN) ? nbeg + npw : kN;
  if (nbeg >= kN) return;
  for (int n0 = nbeg; n0 < nend; ++n0) {
    const int n = rfl(n0);
    const int p0 = rfl(rowstart[n]);
    const int p1 = rfl(rowstart[n + 1]);
    float acc = 0.f;
    int p = p0;
    for (; p + 3 < p1; p += 4) {
      const int s0 = rfl(srcs[p]),     s1 = rfl(srcs[p + 1]);
      const int s2 = rfl(srcs[p + 2]), s3 = rfl(srcs[p + 3]);
      const float e0 = __bfloat162float(ea[(size_t)p * 64 + lane]);
      const float e1 = __bfloat162float(ea[(size_t)(p + 1) * 64 + lane]);
      const float e2 = __bfloat162float(ea[(size_t)(p + 2) * 64 + lane]);
      const float e3 = __bfloat162float(ea[(size_t)(p + 3) * 64 + lane]);
      const float h0 = h[(size_t)s0 * 64 + lane];
      const float h1 = h[(size_t)s1 * 64 + lane];
      const float h2 = h[(size_t)s2 * 64 + lane];
      const float h3 = h[(size_t)s3 * 64 + lane];
      acc += fmaxf(e0 + h0, 0.f) + fmaxf(e1 + h1, 0.f)
           + fmaxf(e2 + h2, 0.f) + fmaxf(e3 + h3, 0.f);
    }
    for (; p < p1; ++p) {
      const int s = rfl(srcs[p]);
      acc += fmaxf(__bfloat162float(ea[(size_t)p * 64 + lane])
                   + h[(size_t)s * 64 + lane], 0.f);
    }
    agg[(size_t)n * 64 + lane] = acc;
  }
}

// ---------------------------------------------------------------------------
// z1 = relu((h+agg) @ w1 + b1)       [1e5,64]@[64,64]
// ---------------------------------------------------------------------------
__global__ __launch_bounds__(256) void k_gemm1(const float* __restrict__ h,
                                               const float* __restrict__ agg,
                                               const float* __restrict__ w,
                                               const float* __restrict__ b,
                                               float* __restrict__ z1) {
  const int lane = threadIdx.x & 63;
  const int wid  = blockIdx.x * (blockDim.x >> 6) + (threadIdx.x >> 6);
  const int nw   = gridDim.x * (blockDim.x >> 6);
  float wreg[64];
#pragma unroll
  for (int k = 0; k < 64; ++k) wreg[k] = w[k * 64 + lane];
  const float bias = b[lane];
  const int npw  = (kN + nw - 1) / nw;
  const int nbeg = wid * npw;
  const int nend = (nbeg + npw < kN) ? nbeg + npw : kN;
  for (int n0 = nbeg; n0 < nend; ++n0) {
    const int n = rfl(n0);
    const float* __restrict__ hr = h   + (size_t)n * 64;
    const float* __restrict__ ar = agg + (size_t)n * 64;
    float a0 = bias, a1 = 0.f;
#pragma unroll
    for (int k = 0; k < 64; k += 2) {
      a0 = fmaf(hr[k]     + ar[k],     wreg[k],     a0);
      a1 = fmaf(hr[k + 1] + ar[k + 1], wreg[k + 1], a1);
    }
    z1[(size_t)n * 64 + lane] = fmaxf(a0 + a1, 0.f);
  }
}

// ---------------------------------------------------------------------------
// z = z1 @ w2 + b2, plus per-channel sum / sumsq partials for BatchNorm.
// ---------------------------------------------------------------------------
__global__ __launch_bounds__(256) void k_gemm2(const float* __restrict__ z1,
                                               const float* __restrict__ w,
                                               const float* __restrict__ b,
                                               float* __restrict__ z,
                                               float* __restrict__ bnsum,
                                               float* __restrict__ bnsq) {
  __shared__ float redS[4][64];
  __shared__ float redQ[4][64];
  const int lane = threadIdx.x & 63;
  const int wv   = threadIdx.x >> 6;
  const int wid  = blockIdx.x * (blockDim.x >> 6) + wv;
  const int nw   = gridDim.x * (blockDim.x >> 6);
  float wreg[64];
#pragma unroll
  for (int k = 0; k < 64; ++k) wreg[k] = w[k * 64 + lane];
  const float bias = b[lane];
  float lsum = 0.f, lsq = 0.f;
  const int npw  = (kN + nw - 1) / nw;
  const int nbeg = wid * npw;
  const int nend = (nbeg + npw < kN) ? nbeg + npw : kN;
  for (int n0 = nbeg; n0 < nend; ++n0) {
    const int n = rfl(n0);
    const float* __restrict__ r = z1 + (size_t)n * 64;
    float a0 = bias, a1 = 0.f;
#pragma unroll
    for (int k = 0; k < 64; k += 2) {
      a0 = fmaf(r[k],     wreg[k],     a0);
      a1 = fmaf(r[k + 1], wreg[k + 1], a1);
    }
    const float zv = a0 + a1;
    z[(size_t)n * 64 + lane] = zv;
    lsum += zv;
    lsq = fmaf(zv, zv, lsq);
  }
  redS[wv][lane] = lsum;
  redQ[wv][lane] = lsq;
  __syncthreads();
  if (threadIdx.x < 64) {
    float s = redS[0][lane] + redS[1][lane] + redS[2][lane] + redS[3][lane];
    float q = redQ[0][lane] + redQ[1][lane] + redQ[2][lane] + redQ[3][lane];
    atomicAdd(&bnsum[lane], s);
    atomicAdd(&bnsq[lane], q);
  }
}

// ---------------------------------------------------------------------------
// BN finalize: per-channel scale/shift from global sums.
// ---------------------------------------------------------------------------
__global__ void k_bnfin(const float* __restrict__ s, const float* __restrict__ q,
                        const float* __restrict__ gm, const float* __restrict__ bt,
                        float* __restrict__ scale, float* __restrict__ shift) {
  const int c = threadIdx.x;
  const float inv = 1.0f / (float)kN;
  const float mean = s[c] * inv;
  float var = q[c] * inv - mean * mean;
  var = fmaxf(var, 0.f);
  const float sc = gm[c] * rsqrtf(var + 1e-5f);
  scale[c] = sc;
  shift[c] = bt[c] - mean * sc;
}

// ---------------------------------------------------------------------------
// h = (h + relu(z*scale + shift)) * 0.5   (elementwise, float4)
// ---------------------------------------------------------------------------
__global__ __launch_bounds__(256) void k_bnapply(const float* __restrict__ z,
                                                 float* __restrict__ h,
                                                 const float* __restrict__ scale,
                                                 const float* __restrict__ shift) {
  __shared__ float sc[64], sh[64];
  if (threadIdx.x < 64) { sc[threadIdx.x] = scale[threadIdx.x]; sh[threadIdx.x] = shift[threadIdx.x]; }
  __syncthreads();
  const size_t tid    = (size_t)blockIdx.x * blockDim.x + threadIdx.x;
  const size_t stride = (size_t)gridDim.x * blockDim.x;
  const size_t total  = (size_t)kN * 16;  // float4 groups
  for (size_t i = tid; i < total; i += stride) {
    const int c0 = (int)((i * 4) & 63);
    const float4 zv = ((const float4*)z)[i];
    float4 hv = ((float4*)h)[i];
    hv.x = (hv.x + fmaxf(fmaf(zv.x, sc[c0 + 0], sh[c0 + 0]), 0.f)) * 0.5f;
    hv.y = (hv.y + fmaxf(fmaf(zv.y, sc[c0 + 1], sh[c0 + 1]), 0.f)) * 0.5f;
    hv.z = (hv.z + fmaxf(fmaf(zv.z, sc[c0 + 2], sh[c0 + 2]), 0.f)) * 0.5f;
    hv.w = (hv.w + fmaxf(fmaf(zv.w, sc[c0 + 3], sh[c0 + 3]), 0.f)) * 0.5f;
    ((float4*)h)[i] = hv;
  }
}

// ---------------------------------------------------------------------------
// Head stage A:
// f1 = relu( relu(h[a])@W1[0:64] + relu(h[b])@W1[64:128] + eattr@Wp + b1 + bp )
// ---------------------------------------------------------------------------
__global__ __launch_bounds__(256) void k_headA(const float* __restrict__ h,
                                               const int* __restrict__ ei,
                                               const float* __restrict__ eattr,
                                               const float* __restrict__ W1,
                                               const float* __restrict__ b1,
                                               const float* __restrict__ Wp,
                                               const float* __restrict__ bp,
                                               float* __restrict__ f1out) {
  const int lane = threadIdx.x & 63;
  const int wid  = blockIdx.x * (blockDim.x >> 6) + (threadIdx.x >> 6);
  const int nw   = gridDim.x * (blockDim.x >> 6);
  float wa[64], wb[64], wp[32];
#pragma unroll
  for (int k = 0; k < 64; ++k) wa[k] = W1[k * 64 + lane];
#pragma unroll
  for (int k = 0; k < 64; ++k) wb[k] = W1[(64 + k) * 64 + lane];
#pragma unroll
  for (int k = 0; k < 32; ++k) wp[k] = Wp[k * 64 + lane];
  const float bias = b1[lane] + bp[lane];
  const int epw  = (kEP + nw - 1) / nw;
  const int ebeg = wid * epw;
  const int eend = (ebeg + epw < kEP) ? ebeg + epw : kEP;
  for (int e0 = ebeg; e0 < eend; ++e0) {
    const int e = rfl(e0);
    const int a     = rfl(ei[e]);
    const int bnode = rfl(ei[kEP + e]);
    const float* __restrict__ ha = h + (size_t)a * 64;
    const float* __restrict__ hb = h + (size_t)bnode * 64;
    const float* __restrict__ row = eattr + (size_t)e * 32;
    float a0 = bias, a1 = 0.f, a2 = 0.f;
#pragma unroll
    for (int k = 0; k < 64; ++k) a0 = fmaf(fmaxf(ha[k], 0.f), wa[k], a0);
#pragma unroll
    for (int k = 0; k < 64; ++k) a1 = fmaf(fmaxf(hb[k], 0.f), wb[k], a1);
#pragma unroll
    for (int k = 0; k < 32; ++k) a2 = fmaf(row[k], wp[k], a2);
    f1out[(size_t)e * 64 + lane] = fmaxf(a0 + a1 + a2, 0.f);
  }
}

// ---------------------------------------------------------------------------
// Head stage B: f2 = relu(f1@mlp2+b2) [25]; out = sigmoid(f2@mlp3+b3)
// ---------------------------------------------------------------------------
__global__ __launch_bounds__(256) void k_headB(const float* __restrict__ f1,
                                               const float* __restrict__ W2,
                                               const float* __restrict__ b2,
                                               const float* __restrict__ W3,
                                               const float* __restrict__ b3,
                                               float* __restrict__ out) {
  const int lane = threadIdx.x & 63;
  const int wid  = blockIdx.x * (blockDim.x >> 6) + (threadIdx.x >> 6);
  const int nw   = gridDim.x * (blockDim.x >> 6);
  const int c = (lane < 25) ? lane : 0;
  float w2r[64];
#pragma unroll
  for (int k = 0; k < 64; ++k) w2r[k] = W2[k * 25 + c];
  const float bias2 = b2[c];
  const float w3v = (lane < 25) ? W3[lane] : 0.0f;
  const float b3v = b3[0];
  const int epw  = (kEP + nw - 1) / nw;
  const int ebeg = wid * epw;
  const int eend = (ebeg + epw < kEP) ? ebeg + epw : kEP;
  for (int e0 = ebeg; e0 < eend; ++e0) {
    const int e = rfl(e0);
    const float* __restrict__ r = f1 + (size_t)e * 64;
    float a0 = bias2, a1 = 0.f;
#pragma unroll
    for (int k = 0; k < 64; k += 2) {
      a0 = fmaf(r[k],     w2r[k],     a0);
      a1 = fmaf(r[k + 1], w2r[k + 1], a1);
    }
    float p = fmaxf(a0 + a1, 0.f) * w3v;   // lanes >=25 contribute 0
#pragma unroll
    for (int off = 32; off; off >>= 1) p += __shfl_xor(p, off, 64);
    if (lane == 0) out[e] = 1.0f / (1.0f + expf(-(p + b3v)));
  }
}

// ---------------------------------------------------------------------------
extern "C" void kernel_launch(void* const* d_in, const int* in_sizes, int n_in,
                              void* d_out, int out_size, void* d_ws, size_t ws_size,
                              hipStream_t stream) {
  const float* x      = (const float*)d_in[0];
  const int*   ei     = (const int*)  d_in[1];
  const float* eattr  = (const float*)d_in[2];
  const int*   pei    = (const int*)  d_in[3];
  const float* peat   = (const float*)d_in[4];
  const int*   nei    = (const int*)  d_in[5];
  const float* neat   = (const float*)d_in[6];
  const float* node_w = (const float*)d_in[7];
  const float* node_b = (const float*)d_in[8];
  const float* edge_w = (const float*)d_in[9];
  const float* edge_b = (const float*)d_in[10];
  const float* conv_w1= (const float*)d_in[11];
  const float* conv_b1= (const float*)d_in[12];
  const float* conv_w2= (const float*)d_in[13];
  const float* conv_b2= (const float*)d_in[14];
  const float* gamma  = (const float*)d_in[15];
  const float* beta   = (const float*)d_in[16];
  const float* m1w    = (const float*)d_in[17];
  const float* m1b    = (const float*)d_in[18];
  const float* m2w    = (const float*)d_in[19];
  const float* m2b    = (const float*)d_in[20];
  const float* m3w    = (const float*)d_in[21];
  const float* m3b    = (const float*)d_in[22];

  float* out_pos = (float*)d_out;
  float* out_neg = out_pos + kEP;
  float* h       = out_neg + kEP;          // [N,64] lives in d_out

  // ---- workspace carve-out (alignment-aware; ~214 MB total) ----
  size_t off = 0;
  auto alloc = [&](size_t bytes, size_t align) -> void* {
    off = (off + align - 1) / align * align;
    void* p = (char*)d_ws + off;
    off += bytes;
    return p;
  };
  float* agg      = (float*)alloc((size_t)kN * 64 * 4, 16);
  float* z1       = (float*)alloc((size_t)kN * 64 * 4, 16);   // reused as f1_pos
  float* zz       = (float*)alloc((size_t)kN * 64 * 4, 16);   // reused as f1_neg
  float* bnsum    = (float*)alloc(64 * 4, 16);
  float* bnsq     = (float*)alloc(64 * 4, 16);
  float* scale    = (float*)alloc(64 * 4, 16);
  float* shift    = (float*)alloc(64 * 4, 16);
  float* Wp       = (float*)alloc(32 * 64 * 4, 16);
  float* bp       = (float*)alloc(64 * 4, 16);
  int*   deg      = (int*)  alloc((size_t)kN * 4, 16);        // reused as cursor
  int*   rowstart = (int*)  alloc((size_t)(kN + 1) * 4, 16);
  int*   btot     = (int*)  alloc(128 * 4, 16);
  int*   boff     = (int*)  alloc(128 * 4, 16);
  int*   eperm    = (int*)  alloc((size_t)kE * 4, 16);
  int*   srcs     = (int*)  alloc((size_t)kE * 4, 16);
  __hip_bfloat16* ea = (__hip_bfloat16*)alloc((size_t)kE * 64 * 2, 16);
  (void)ws_size;  // verified: harness ws is large enough (~214 MB needed)

  k_head_pre<<<dim3(33), dim3(64), 0, stream>>>(edge_w, edge_b, m1w, Wp, bp);
  k_node_enc<<<dim3(1024), dim3(256), 0, stream>>>(x, node_w, node_b, h);

  // ---- CSR build (layer-invariant) ----
  hipMemsetAsync(deg, 0, kN * sizeof(int), stream);
  k_hist<<<dim3(2048), dim3(256), 0, stream>>>(ei, deg);
  k_scanA<<<dim3(SCAN_NB), dim3(1024), 0, stream>>>(deg, rowstart, btot);
  k_scanB<<<dim3(1), dim3(128), 0, stream>>>(btot, boff);
  k_scanC<<<dim3(SCAN_NB), dim3(1024), 0, stream>>>(rowstart, boff);
  hipMemsetAsync(deg, 0, kN * sizeof(int), stream);   // reuse as cursor
  k_fill<<<dim3(2048), dim3(256), 0, stream>>>(ei, rowstart, deg, eperm, srcs);
  k_edge_emb<<<dim3(2048), dim3(256), 0, stream>>>(eperm, eattr, edge_w, edge_b, ea);

  for (int l = 0; l < 2; ++l) {
    hipMemsetAsync(bnsum, 0, 128 * sizeof(float), stream);
    k_aggr_s<<<dim3(2048), dim3(256), 0, stream>>>(h, ea, srcs, rowstart, agg);
    k_gemm1<<<dim3(1024), dim3(256), 0, stream>>>(h, agg, conv_w1 + l * 4096,
                                                  conv_b1 + l * 64, z1);
    k_gemm2<<<dim3(1024), dim3(256), 0, stream>>>(z1, conv_w2 + l * 4096,
                                                  conv_b2 + l * 64, zz, bnsum, bnsq);
    k_bnfin<<<dim3(1), dim3(64), 0, stream>>>(bnsum, bnsq, gamma + l * 64,
                                              beta + l * 64, scale, shift);
    k_bnapply<<<dim3(2048), dim3(256), 0, stream>>>(zz, h, scale, shift);
  }

  // heads: f1 into z1 (pos) / zz (neg), then MLP2/3 + sigmoid
  k_headA<<<dim3(1024), dim3(256), 0, stream>>>(h, pei, peat, m1w, m1b, Wp, bp, z1);
  k_headA<<<dim3(1024), dim3(256), 0, stream>>>(h, nei, neat, m1w, m1b, Wp, bp, zz);
  k_headB<<<dim3(1024), dim3(256), 0, stream>>>(z1, m2w, m2b, m3w, m3b, out_pos);
  k_headB<<<dim3(1024), dim3(256), 0, stream>>>(zz, m2w, m2b, m3w, m3b, out_neg);
}